// Round 13
// baseline (597.081 us; speedup 1.0000x reference)
//
#include <hip/hip_runtime.h>
#include <stdint.h>

#define B_ 512
#define D_ 512
#define C_ 100000
#define CK_ 300000
#define S_ 30.0f
#define COSM_ 0.8775825618903728f
#define SINM_ 0.4794255386042030f
#define TH_ (-0.8775825618903728f)
#define MM_ 0.2397127693021015f
#define EPS_ 1e-12f

#define BM 256
#define BN 96
#define BK 32
#define BUFU 14336  /* ushorts/buffer: A 256x32 bf16 (8192) + B 96x32 fp32 (6144) */

typedef float f32x4 __attribute__((ext_vector_type(4)));
typedef short s16x8 __attribute__((ext_vector_type(8)));
typedef unsigned long long u64;
typedef unsigned int u32;

#define GLL16(g, l) __builtin_amdgcn_global_load_lds( \
    (const __attribute__((address_space(1))) void*)(g), \
    (__attribute__((address_space(3))) void*)(l), 16, 0, 0)

__device__ __forceinline__ unsigned short f2bf(float f){
  u32 u = __float_as_uint(f);
  u += 0x7FFFu + ((u >> 16) & 1u);
  return (unsigned short)(u >> 16);
}

// ---------------- normalize x rows -> unit bf16 ----------------
__global__ void k_normx(const float* __restrict__ x, unsigned short* __restrict__ xn){
  int row  = blockIdx.x * 4 + (threadIdx.x >> 6);
  int lane = threadIdx.x & 63;
  const float* xr = x + (size_t)row * D_ + lane * 8;
  float4 v0 = *(const float4*)xr;
  float4 v1 = *(const float4*)(xr + 4);
  float s = v0.x*v0.x + v0.y*v0.y + v0.z*v0.z + v0.w*v0.w
          + v1.x*v1.x + v1.y*v1.y + v1.z*v1.z + v1.w*v1.w;
  #pragma unroll
  for (int off = 1; off < 64; off <<= 1) s += __shfl_xor(s, off);
  float inv = 1.f / fmaxf(sqrtf(s), EPS_);
  s16x8 h;
  h[0] = (short)f2bf(v0.x*inv); h[1] = (short)f2bf(v0.y*inv);
  h[2] = (short)f2bf(v0.z*inv); h[3] = (short)f2bf(v0.w*inv);
  h[4] = (short)f2bf(v1.x*inv); h[5] = (short)f2bf(v1.y*inv);
  h[6] = (short)f2bf(v1.z*inv); h[7] = (short)f2bf(v1.w*inv);
  *(s16x8*)(xn + (size_t)row * D_ + lane * 8) = h;
}

// ---------------- zero the per-row reduction buffers ----------------
__global__ void k_init(float* __restrict__ sumexp, u64* __restrict__ packed,
                       float* __restrict__ phi){
  int i = threadIdx.x;
  sumexp[i] = 0.f;
  packed[i] = 0ull;
  phi[i]    = 0.f;
}

// ======= single-pass GEMM, 8 waves, 2-phase-per-K-tile interleave, 3-buf, counted vmcnt =======
__global__ __launch_bounds__(512, 2) void k_gemm(
    const unsigned short* __restrict__ xn, const float* __restrict__ w,
    const int* __restrict__ label,
    float* __restrict__ sumexp_g, u64* __restrict__ packed_g,
    float* __restrict__ phi_g)
{
  __shared__ unsigned short st[3*BUFU];   // 86016 B triple-buffered
  __shared__ int slab[BM];
  float* mx = (float*)st;                 // epilogue overlay [256][33] = 33792 B

  // bijective XCD-chunked mapping: 6250 blocks = 8*781 + 2
  const int bid = blockIdx.x;
  const int xcd = bid & 7;
  const int i8  = bid >> 3;
  const int seq = (xcd < 2) ? (xcd*782 + i8) : (1564 + (xcd-2)*781 + i8);
  const int ct = seq >> 1;                 // column tile (32 classes)
  const int rt = seq & 1;                  // row tile (256 rows)
  const int rowbase = rt * BM;
  const int lcbase  = ct * 32;

  const int tid  = threadIdx.x;
  const int lane = tid & 63;
  const int wid  = tid >> 6;                 // 0..7
  const int wm   = wid >> 1, wn = wid & 1;   // 4x2 wave grid, wave tile 64x48
  const int lc15 = lane & 15, lhi = lane >> 4;

  if (tid < BM) slab[tid] = label[rowbase + tid];

  // ---- A staging (2 gl_lds/tile): slot s = p*512+tid; frag fa=s>>6; lane l=s&63
  const unsigned short* asrc[2]; int adst[2];
  #pragma unroll
  for (int p = 0; p < 2; ++p){
    int s  = p*512 + tid;
    int fa = s >> 6, l = s & 63;
    asrc[p] = xn + (size_t)(rowbase + fa*16 + (l & 15)) * D_ + (l >> 4)*8;
    adst[p] = s*8;                          // ushort idx, linear
  }
  // ---- B staging (2 gl_lds/tile, 768 slots, dup for uniformity): slot->frag fb, half h
  const float* bsrc[2]; int bdst[2];
  #pragma unroll
  for (int p = 0; p < 2; ++p){
    int slot = (p == 0) ? tid : (tid < 256 ? 512 + tid : tid - 256);
    int fb = slot >> 7, h = (slot >> 6) & 1, l = slot & 63;
    int wrow = ct*BN + ((fb/3)*16 + (l & 15))*3 + (fb % 3);  // class-permuted
    bsrc[p] = w + (size_t)wrow * D_ + (l >> 4)*8 + h*4;
    bdst[p] = 8192 + slot*8;                // ushort idx, linear
  }

  // ---- fragment read offsets: base + lane*16B (conflict-free by construction)
  int aoff[4];
  #pragma unroll
  for (int m = 0; m < 4; ++m) aoff[m] = (wm*4 + m)*512 + lane*8;        // ushort idx
  int bqoff[3][2];
  #pragma unroll
  for (int n = 0; n < 3; ++n)
    #pragma unroll
    for (int h = 0; h < 2; ++h)
      bqoff[n][h] = 4096 + (wn*3 + n)*512 + h*256 + lane*4;             // float idx

  f32x4 acc[4][3] = {};
  float sq0 = 0.f, sq1 = 0.f, sq2 = 0.f;

#define CVT3(DST, QA, QB, SQ) do{ \
    u32 c0_, c1_, c2_, c3_; \
    asm("v_cvt_pk_bf16_f32 %0, %1, %2" : "=v"(c0_) : "v"(QA[0]), "v"(QA[1])); \
    asm("v_cvt_pk_bf16_f32 %0, %1, %2" : "=v"(c1_) : "v"(QA[2]), "v"(QA[3])); \
    asm("v_cvt_pk_bf16_f32 %0, %1, %2" : "=v"(c2_) : "v"(QB[0]), "v"(QB[1])); \
    asm("v_cvt_pk_bf16_f32 %0, %1, %2" : "=v"(c3_) : "v"(QB[2]), "v"(QB[3])); \
    union { s16x8 h; u32 u[4]; } pk_; \
    pk_.u[0] = c0_; pk_.u[1] = c1_; pk_.u[2] = c2_; pk_.u[3] = c3_; \
    DST = pk_.h; \
    SQ += QA[0]*QA[0] + QA[1]*QA[1] + QA[2]*QA[2] + QA[3]*QA[3] \
        + QB[0]*QB[0] + QB[1]*QB[1] + QB[2]*QB[2] + QB[3]*QB[3]; \
  }while(0)

  // ---- prologue: stage tiles 0,1; wait tile 0 only (tile 1 stays in flight)
  GLL16(asrc[0], &st[adst[0]]);          GLL16(asrc[1], &st[adst[1]]);
  GLL16(bsrc[0], &st[bdst[0]]);          GLL16(bsrc[1], &st[bdst[1]]);
  GLL16(asrc[0] + BK, &st[BUFU+adst[0]]); GLL16(asrc[1] + BK, &st[BUFU+adst[1]]);
  GLL16(bsrc[0] + BK, &st[BUFU+bdst[0]]); GLL16(bsrc[1] + BK, &st[BUFU+bdst[1]]);
  asm volatile("s_waitcnt vmcnt(4)" ::: "memory");
  __builtin_amdgcn_s_barrier();

  #pragma unroll
  for (int kt = 0; kt < 16; ++kt){
    const unsigned short* ab = &st[(kt % 3)*BUFU];
    const float* bb = (const float*)ab;
    // ======== phase 0: ds_read {a0,a1, B fp32} || issue A(t+2); 6 MFMA ========
    s16x8 a0 = *(const s16x8*)(ab + aoff[0]);
    s16x8 a1 = *(const s16x8*)(ab + aoff[1]);
    f32x4 q00 = *(const f32x4*)(bb + bqoff[0][0]);
    f32x4 q01 = *(const f32x4*)(bb + bqoff[0][1]);
    f32x4 q10 = *(const f32x4*)(bb + bqoff[1][0]);
    f32x4 q11 = *(const f32x4*)(bb + bqoff[1][1]);
    f32x4 q20 = *(const f32x4*)(bb + bqoff[2][0]);
    f32x4 q21 = *(const f32x4*)(bb + bqoff[2][1]);
    if (kt < 14){
      const int b2 = ((kt+2) % 3)*BUFU, k2 = (kt+2)*BK;
      GLL16(asrc[0] + k2, &st[b2 + adst[0]]);
      GLL16(asrc[1] + k2, &st[b2 + adst[1]]);
    }
    asm volatile("" ::: "memory");
    __builtin_amdgcn_s_barrier();
    s16x8 bfr0, bfr1, bfr2;
    CVT3(bfr0, q00, q01, sq0);
    CVT3(bfr1, q10, q11, sq1);
    CVT3(bfr2, q20, q21, sq2);
    __builtin_amdgcn_s_setprio(1);
    acc[0][0] = __builtin_amdgcn_mfma_f32_16x16x32_bf16(a0, bfr0, acc[0][0], 0,0,0);
    acc[0][1] = __builtin_amdgcn_mfma_f32_16x16x32_bf16(a0, bfr1, acc[0][1], 0,0,0);
    acc[0][2] = __builtin_amdgcn_mfma_f32_16x16x32_bf16(a0, bfr2, acc[0][2], 0,0,0);
    acc[1][0] = __builtin_amdgcn_mfma_f32_16x16x32_bf16(a1, bfr0, acc[1][0], 0,0,0);
    acc[1][1] = __builtin_amdgcn_mfma_f32_16x16x32_bf16(a1, bfr1, acc[1][1], 0,0,0);
    acc[1][2] = __builtin_amdgcn_mfma_f32_16x16x32_bf16(a1, bfr2, acc[1][2], 0,0,0);
    __builtin_amdgcn_s_setprio(0);
    asm volatile("" ::: "memory");
    __builtin_amdgcn_s_barrier();
    // ======== phase 1: ds_read {a2,a3} || issue B(t+2); vmcnt(4); 6 MFMA ========
    s16x8 a2 = *(const s16x8*)(ab + aoff[2]);
    s16x8 a3 = *(const s16x8*)(ab + aoff[3]);
    if (kt < 14){
      const int b2 = ((kt+2) % 3)*BUFU, k2 = (kt+2)*BK;
      GLL16(bsrc[0] + k2, &st[b2 + bdst[0]]);
      GLL16(bsrc[1] + k2, &st[b2 + bdst[1]]);
      asm volatile("s_waitcnt vmcnt(4)" ::: "memory");   // tile t+1 landed; t+2 in flight
    } else if (kt == 14){
      asm volatile("s_waitcnt vmcnt(0)" ::: "memory");   // tail: tile 15 landed
    }
    asm volatile("" ::: "memory");
    __builtin_amdgcn_s_barrier();
    __builtin_amdgcn_s_setprio(1);
    acc[2][0] = __builtin_amdgcn_mfma_f32_16x16x32_bf16(a2, bfr0, acc[2][0], 0,0,0);
    acc[2][1] = __builtin_amdgcn_mfma_f32_16x16x32_bf16(a2, bfr1, acc[2][1], 0,0,0);
    acc[2][2] = __builtin_amdgcn_mfma_f32_16x16x32_bf16(a2, bfr2, acc[2][2], 0,0,0);
    acc[3][0] = __builtin_amdgcn_mfma_f32_16x16x32_bf16(a3, bfr0, acc[3][0], 0,0,0);
    acc[3][1] = __builtin_amdgcn_mfma_f32_16x16x32_bf16(a3, bfr1, acc[3][1], 0,0,0);
    acc[3][2] = __builtin_amdgcn_mfma_f32_16x16x32_bf16(a3, bfr2, acc[3][2], 0,0,0);
    __builtin_amdgcn_s_setprio(0);
    asm volatile("" ::: "memory");
    __builtin_amdgcn_s_barrier();
  }
#undef CVT3

  // ---- weight-row inverse norms: fold k-slice lanes (bits 4,5) — per-wave exact copy
  float inv_[3];
  {
    sq0 += __shfl_xor(sq0, 16); sq0 += __shfl_xor(sq0, 32);
    sq1 += __shfl_xor(sq1, 16); sq1 += __shfl_xor(sq1, 32);
    sq2 += __shfl_xor(sq2, 16); sq2 += __shfl_xor(sq2, 32);
    inv_[0] = 1.f / fmaxf(sqrtf(sq0), EPS_);
    inv_[1] = 1.f / fmaxf(sqrtf(sq1), EPS_);
    inv_[2] = 1.f / fmaxf(sqrtf(sq2), EPS_);
  }

  // ---- subcenter max in-register; phi at label; write mx (overlay, post-barrier)
  {
    int cls = wn*16 + lc15;
    #pragma unroll
    for (int m = 0; m < 4; ++m){
      #pragma unroll
      for (int r = 0; r < 4; ++r){
        int rl = wm*64 + m*16 + lhi*4 + r;
        float v = fmaxf(fmaxf(acc[m][0][r]*inv_[0], acc[m][1][r]*inv_[1]), acc[m][2][r]*inv_[2]);
        if (slab[rl] - lcbase == cls){
          float cy = v;
          float s2 = fminf(fmaxf(1.f - cy*cy, 0.f), 1.f);
          float sy = sqrtf(s2);
          float ph = cy*COSM_ - sy*SINM_;
          if (!(cy - TH_ > 0.f)) ph = cy - MM_;
          phi_g[rowbase + rl] = ph;        // unique writer
          v = ph;
        }
        mx[rl*33 + cls] = v;
      }
    }
  }
  __syncthreads();

  // ---- per-row LSE + argmax over this block's 32 classes: 2 threads per row
  {
    int row  = tid >> 1;
    int half = tid & 1;
    int grow = rowbase + row;
    float se = 0.f;
    u64 pk = 0ull;
    #pragma unroll
    for (int c = 0; c < 16; ++c){
      int lc = half*16 + c;
      float v = mx[row*33 + lc];
      se += __expf(S_*v - S_);
      u32 u = __float_as_uint(v);
      u = (v >= 0.f) ? (u | 0x80000000u) : ~u;            // sortable float
      u64 p = ((u64)u << 32) | (u32)~(u32)(lcbase + lc);  // ~idx: first-occurrence ties
      pk = (p > pk) ? p : pk;
    }
    se += __shfl_xor(se, 1);
    u32 lo = (u32)pk, hi2 = (u32)(pk >> 32);
    u32 plo = __shfl_xor(lo, 1), phi2 = __shfl_xor(hi2, 1);
    u64 po = ((u64)phi2 << 32) | plo;
    pk = (po > pk) ? po : pk;
    if (half == 0){
      atomicAdd(&sumexp_g[grow], se);
      atomicMax(&packed_g[grow], pk);
    }
  }
}

// ---------------- finalize: loss + prec1 ----------------
__global__ void k_final(const float* __restrict__ sumexp, const u64* __restrict__ packed,
                        const float* __restrict__ phi, const int* __restrict__ label,
                        float* __restrict__ out){
  int i = threadIdx.x;
  float lse  = S_ + logf(sumexp[i]);
  float loss = lse - S_ * phi[i];
  u32 pred = ~(u32)(packed[i] & 0xFFFFFFFFull);
  float corr = (pred == (u32)label[i]) ? 1.f : 0.f;
  float a = loss, b = corr;
  #pragma unroll
  for (int off = 1; off < 64; off <<= 1){ a += __shfl_xor(a, off); b += __shfl_xor(b, off); }
  __shared__ float sa[8], sb[8];
  if ((i & 63) == 0){ sa[i >> 6] = a; sb[i >> 6] = b; }
  __syncthreads();
  if (i == 0){
    float ta = 0.f, tb = 0.f;
    #pragma unroll
    for (int j = 0; j < 8; ++j){ ta += sa[j]; tb += sb[j]; }
    out[0] = ta / 512.f;
    out[1] = tb * (100.f / 512.f);
  }
}

extern "C" void kernel_launch(void* const* d_in, const int* in_sizes, int n_in,
                              void* d_out, int out_size, void* d_ws, size_t ws_size,
                              hipStream_t stream){
  const float* x     = (const float*)d_in[0];
  const int*   label = (const int*)d_in[1];
  const float* w     = (const float*)d_in[2];
  float* out = (float*)d_out;
  char* ws = (char*)d_ws;

  unsigned short* xn = (unsigned short*)ws;            // 524288 B
  float* sumexp = (float*)(ws + 524288);               // 2048 B
  u64*   packed = (u64*)(ws + 524288 + 2048);          // 4096 B
  float* phi    = (float*)(ws + 524288 + 2048 + 4096); // 2048 B

  k_init <<<1,    512, 0, stream>>>(sumexp, packed, phi);
  k_normx<<<B_/4, 256, 0, stream>>>(x, xn);
  k_gemm <<<(CK_/BN)*2, 512, 0, stream>>>(xn, w, label, sumexp, packed, phi);
  k_final<<<1,    512, 0, stream>>>(sumexp, packed, phi, label, out);
}

// Round 14
// 504.024 us; speedup vs baseline: 1.1846x; 1.1846x over previous
//
#include <hip/hip_runtime.h>
#include <stdint.h>

#define B_ 512
#define D_ 512
#define C_ 100000
#define CK_ 300000
#define S_ 30.0f
#define COSM_ 0.8775825618903728f
#define SINM_ 0.4794255386042030f
#define TH_ (-0.8775825618903728f)
#define MM_ 0.2397127693021015f
#define EPS_ 1e-12f

#define BM 128
#define BN 96
#define BK 64
#define BUFU 14336   /* ushorts/buffer: A 128x64 bf16 (8192) + B 96x64 bf16 (6144) */

typedef float f32x4 __attribute__((ext_vector_type(4)));
typedef short s16x8 __attribute__((ext_vector_type(8)));
typedef unsigned long long u64;
typedef unsigned int u32;

#define GLL16(g, l) __builtin_amdgcn_global_load_lds( \
    (const __attribute__((address_space(1))) void*)(g), \
    (__attribute__((address_space(3))) void*)(l), 16, 0, 0)

__device__ __forceinline__ unsigned short f2bf(float f){
  u32 u = __float_as_uint(f);
  u += 0x7FFFu + ((u >> 16) & 1u);
  return (unsigned short)(u >> 16);
}

// ---------------- normalize rows of [nrows, 512] fp32 -> unit bf16 ----------------
__global__ void k_norm(const float* __restrict__ src, unsigned short* __restrict__ dst){
  int row  = blockIdx.x * 4 + (threadIdx.x >> 6);
  int lane = threadIdx.x & 63;
  const float* r = src + (size_t)row * D_ + lane * 8;
  float4 v0 = *(const float4*)r;
  float4 v1 = *(const float4*)(r + 4);
  float s = v0.x*v0.x + v0.y*v0.y + v0.z*v0.z + v0.w*v0.w
          + v1.x*v1.x + v1.y*v1.y + v1.z*v1.z + v1.w*v1.w;
  #pragma unroll
  for (int off = 1; off < 64; off <<= 1) s += __shfl_xor(s, off);
  float inv = 1.f / fmaxf(sqrtf(s), EPS_);
  s16x8 h;
  h[0] = (short)f2bf(v0.x*inv); h[1] = (short)f2bf(v0.y*inv);
  h[2] = (short)f2bf(v0.z*inv); h[3] = (short)f2bf(v0.w*inv);
  h[4] = (short)f2bf(v1.x*inv); h[5] = (short)f2bf(v1.y*inv);
  h[6] = (short)f2bf(v1.z*inv); h[7] = (short)f2bf(v1.w*inv);
  *(s16x8*)(dst + (size_t)row * D_ + lane * 8) = h;
}

// ---------------- zero the per-row reduction buffers ----------------
__global__ void k_init(float* __restrict__ sumexp, u64* __restrict__ packed,
                       float* __restrict__ phi){
  int i = threadIdx.x;
  sumexp[i] = 0.f;
  packed[i] = 0ull;
  phi[i]    = 0.f;
}

// ======= PATH A: R6 schedule (dbuf, vmcnt(7), 2 barriers/step) + FRAG-LINEAR LDS =======
// A frag (fa,ks): lane l -> row fa*16+(l&15), k ks*32+(l>>4)*8. slot (fa*2+ks)*64+l.
// B frag (fb,ks): fb = wn_s*3+n_s -> weight row (class wn_s*16+(l&15), subcenter n_s).
__global__ __launch_bounds__(256, 2) void k_gemm4(
    const unsigned short* __restrict__ xn, const unsigned short* __restrict__ wnb,
    const int* __restrict__ label,
    float* __restrict__ sumexp_g, u64* __restrict__ packed_g,
    float* __restrict__ phi_g)
{
  __shared__ unsigned short st[2*BUFU];   // 57344 B double-buffered
  __shared__ int slab[BM];
  float* mx = (float*)st;                 // epilogue overlay [128][33]

  // bijective XCD-chunked mapping (12500 blocks = 8*1562 + 4)
  const int bid = blockIdx.x;
  const int xcd = bid & 7;
  const int i8  = bid >> 3;
  const int seq = (xcd < 4) ? (xcd*1563 + i8) : (6252 + (xcd-4)*1562 + i8);
  const int ct = seq >> 2;                 // column tile 0..3124 (32 classes)
  const int rt = seq & 3;                  // row tile 0..3
  const int rowbase = rt * BM;
  const int lcbase  = ct * 32;

  const int tid  = threadIdx.x;
  const int lane = tid & 63;
  const int wid  = tid >> 6;
  const int wm   = wid >> 1, wn = wid & 1; // 2x2 wave grid, wave tile 64x48
  const int lc15 = lane & 15, lhi = lane >> 4;

  if (tid < BM) slab[tid] = label[rowbase + tid];

  // ---- staging sources (kt-invariant); dest is linear p*2048 + tid*8 (ushorts)
  const unsigned short* asrc[4];
  #pragma unroll
  for (int p = 0; p < 4; ++p){
    int fa2 = p*4 + wid;                   // 0..15
    int fa = fa2 >> 1, ks = fa2 & 1;
    asrc[p] = xn + (size_t)(rowbase + fa*16 + lc15) * D_ + ks*32 + lhi*8;
  }
  const unsigned short* bsrc[3];
  #pragma unroll
  for (int p = 0; p < 3; ++p){
    int fbks = p*4 + wid;                  // 0..11
    int fb = fbks >> 1, ks = fbks & 1;
    int wn_s = fb / 3, n_s = fb % 3;
    int wrow = ct*BN + (wn_s*16 + lc15)*3 + n_s;
    bsrc[p] = wnb + (size_t)wrow * D_ + ks*32 + lhi*8;
  }

  // ---- fragment read offsets: base + lane*16B (conflict-free by construction)
  int aoff[4][2], boff[3][2];
  #pragma unroll
  for (int m = 0; m < 4; ++m)
    #pragma unroll
    for (int ks = 0; ks < 2; ++ks)
      aoff[m][ks] = ((wm*4 + m)*2 + ks)*512 + lane*8;
  #pragma unroll
  for (int n = 0; n < 3; ++n)
    #pragma unroll
    for (int ks = 0; ks < 2; ++ks)
      boff[n][ks] = 8192 + ((wn*3 + n)*2 + ks)*512 + lane*8;

#define STAGE(BUFB, KT) do{                                                  \
    _Pragma("unroll")                                                        \
    for (int p = 0; p < 4; ++p)                                              \
      GLL16(asrc[p] + (KT)*BK, &st[(BUFB) + p*2048 + tid*8]);                \
    _Pragma("unroll")                                                        \
    for (int p = 0; p < 3; ++p)                                              \
      GLL16(bsrc[p] + (size_t)(KT)*BK, &st[(BUFB) + 8192 + p*2048 + tid*8]); \
  }while(0)

  f32x4 acc[4][3] = {};

  // ---- prologue: tile 0 -> buffer 0 (7 loads/thread)
  STAGE(0, 0);

  #pragma unroll
  for (int t = 0; t < 8; ++t){
    if (t < 7){
      STAGE(((t+1)&1)*BUFU, t+1);
      asm volatile("s_waitcnt vmcnt(7)" ::: "memory");   // tile t landed; t+1 in flight
    } else {
      asm volatile("s_waitcnt vmcnt(0)" ::: "memory");
    }
    __builtin_amdgcn_s_barrier();
    asm volatile("" ::: "memory");
    const unsigned short* cb = &st[(t&1)*BUFU];
    #pragma unroll
    for (int ks = 0; ks < 2; ++ks){
      s16x8 af[4], bfr[3];
      #pragma unroll
      for (int m = 0; m < 4; ++m) af[m]  = *(const s16x8*)(cb + aoff[m][ks]);
      #pragma unroll
      for (int n = 0; n < 3; ++n) bfr[n] = *(const s16x8*)(cb + boff[n][ks]);
      __builtin_amdgcn_s_setprio(1);
      #pragma unroll
      for (int m = 0; m < 4; ++m)
        #pragma unroll
        for (int n = 0; n < 3; ++n)
          acc[m][n] = __builtin_amdgcn_mfma_f32_16x16x32_bf16(af[m], bfr[n], acc[m][n], 0, 0, 0);
      __builtin_amdgcn_s_setprio(0);
    }
    asm volatile("" ::: "memory");
    __builtin_amdgcn_s_barrier();
  }
#undef STAGE

  __syncthreads();   // drain before mx overlays the staging buffers

  // acc IS cosine (both operands unit bf16). Subcenter max in-register.
  {
    int cls = wn*16 + lc15;
    #pragma unroll
    for (int m = 0; m < 4; ++m){
      #pragma unroll
      for (int r = 0; r < 4; ++r){
        int rl = wm*64 + m*16 + lhi*4 + r;
        float v = fmaxf(fmaxf(acc[m][0][r], acc[m][1][r]), acc[m][2][r]);
        if (slab[rl] - lcbase == cls){
          float cy = v;
          float s2 = fminf(fmaxf(1.f - cy*cy, 0.f), 1.f);
          float sy = sqrtf(s2);
          float ph = cy*COSM_ - sy*SINM_;
          if (!(cy - TH_ > 0.f)) ph = cy - MM_;
          phi_g[rowbase + rl] = ph;        // unique writer
          v = ph;
        }
        mx[rl*33 + cls] = v;
      }
    }
  }
  __syncthreads();

  // per-row LSE + argmax over this block's 32 classes: 2 threads per row
  {
    int row  = tid >> 1;
    int half = tid & 1;
    int grow = rowbase + row;
    float se = 0.f;
    u64 pk = 0ull;
    #pragma unroll
    for (int c = 0; c < 16; ++c){
      int lc = half*16 + c;
      float v = mx[row*33 + lc];
      se += __expf(S_*v - S_);
      u32 u = __float_as_uint(v);
      u = (v >= 0.f) ? (u | 0x80000000u) : ~u;            // sortable float
      u64 p = ((u64)u << 32) | (u32)~(u32)(lcbase + lc);  // ~idx: first-occurrence ties
      pk = (p > pk) ? p : pk;
    }
    se += __shfl_xor(se, 1);
    u32 lo = (u32)pk, hi2 = (u32)(pk >> 32);
    u32 plo = __shfl_xor(lo, 1), phi2 = __shfl_xor(hi2, 1);
    u64 po = ((u64)phi2 << 32) | plo;
    pk = (po > pk) ? po : pk;
    if (half == 0){
      atomicAdd(&sumexp_g[grow], se);
      atomicMax(&packed_g[grow], pk);
    }
  }
}

// ================= PATH B (fallback, ws too small): fused single-pass kernel =========
__global__ __launch_bounds__(256, 3) void k_gemm_fused(
    const unsigned short* __restrict__ xn, const float* __restrict__ w,
    const int* __restrict__ label,
    float* __restrict__ sumexp_g, u64* __restrict__ packed_g,
    float* __restrict__ phi_g)
{
  __shared__ union {
    struct { unsigned short a[BM*BK]; unsigned short b[BN*BK]; } st;
    float mx[BM*33];
  } sm;
  __shared__ float invs[BN];
  __shared__ int   slab[BM];

  const int bid = blockIdx.x;
  const int xcd = bid & 7;
  const int i8  = bid >> 3;
  const int seq = (xcd < 4) ? (xcd*1563 + i8) : (6252 + (xcd-4)*1562 + i8);
  const int ct = seq >> 2;
  const int rt = seq & 3;
  const int rowbase = rt * BM;
  const int colbase = ct * BN;

  const int tid  = threadIdx.x;
  const int lane = tid & 63;
  const int wid  = tid >> 6;
  const int wm   = wid >> 1, wn = wid & 1;
  const int lc15 = lane & 15, lhi = lane >> 4;

  if (tid < BM) slab[tid] = label[rowbase + tid];

  const int arow0 = tid >> 3, au = tid & 7;
  const unsigned short* asrc0 = xn + (size_t)(rowbase + arow0) * D_ + au * 8;
  const int adst0 = arow0 * BK + ((au * 8) ^ ((arow0 & 7) << 3));

  const int bc = tid >> 4, bu = tid & 15;
  const float* bsrc0 = w + (size_t)(colbase + bc * 3) * D_ + bu * 4;
  const int bdst0 = bc * BK + ((bu * 4) ^ ((bc & 7) << 3));

  const int swz = (lc15 & 7) << 3;
  int aoff[4][2], boff[3][2];
  #pragma unroll
  for (int m = 0; m < 4; ++m){
    int row = wm*64 + m*16 + lc15;
    #pragma unroll
    for (int ks = 0; ks < 2; ++ks) aoff[m][ks] = row * BK + ((ks*32 + lhi*8) ^ swz);
  }
  #pragma unroll
  for (int n = 0; n < 3; ++n){
    int row = wn*48 + n*16 + lc15;
    #pragma unroll
    for (int ks = 0; ks < 2; ++ks) boff[n][ks] = row * BK + ((ks*32 + lhi*8) ^ swz);
  }

  f32x4 acc[4][3] = {};
  float sq[6] = {0.f,0.f,0.f,0.f,0.f,0.f};

  for (int kt = 0; kt < D_/BK; ++kt){
    const int k0 = kt * BK;
    #pragma unroll
    for (int p = 0; p < 4; ++p){
      s16x8 v = *(const s16x8*)(asrc0 + (size_t)p*32*D_ + k0);
      *(s16x8*)(&sm.st.a[adst0 + p*32*BK]) = v;
    }
    #pragma unroll
    for (int p = 0; p < 6; ++p){
      float4 v = *(const float4*)(bsrc0 + (size_t)((p/3)*48 + (p%3)) * D_ + k0);
      sq[p] += v.x*v.x + v.y*v.y + v.z*v.z + v.w*v.w;
      ushort4 h;
      h.x = f2bf(v.x); h.y = f2bf(v.y); h.z = f2bf(v.z); h.w = f2bf(v.w);
      *(ushort4*)(&sm.st.b[bdst0 + p*16*BK]) = h;
    }
    __syncthreads();
    #pragma unroll
    for (int ks = 0; ks < 2; ++ks){
      s16x8 af[4], bfr[3];
      #pragma unroll
      for (int m = 0; m < 4; ++m) af[m]  = *(const s16x8*)(&sm.st.a[aoff[m][ks]]);
      #pragma unroll
      for (int n = 0; n < 3; ++n) bfr[n] = *(const s16x8*)(&sm.st.b[boff[n][ks]]);
      #pragma unroll
      for (int m = 0; m < 4; ++m)
        #pragma unroll
        for (int n = 0; n < 3; ++n)
          acc[m][n] = __builtin_amdgcn_mfma_f32_16x16x32_bf16(af[m], bfr[n], acc[m][n], 0, 0, 0);
    }
    __syncthreads();
  }

  #pragma unroll
  for (int p = 0; p < 6; ++p){
    float s = sq[p];
    s += __shfl_xor(s, 1); s += __shfl_xor(s, 2);
    s += __shfl_xor(s, 4); s += __shfl_xor(s, 8);
    if ((tid & 15) == 0) invs[p*16 + (tid >> 4)] = 1.f / fmaxf(sqrtf(s), EPS_);
  }
  __syncthreads();

  {
    float inv0 = invs[wn*48 +  0 + lc15];
    float inv1 = invs[wn*48 + 16 + lc15];
    float inv2 = invs[wn*48 + 32 + lc15];
    int cls    = wn*16 + lc15;
    int lcb    = ct * 32;
    #pragma unroll
    for (int m = 0; m < 4; ++m){
      #pragma unroll
      for (int r = 0; r < 4; ++r){
        int rl = wm*64 + m*16 + lhi*4 + r;
        float v = fmaxf(fmaxf(acc[m][0][r]*inv0, acc[m][1][r]*inv1), acc[m][2][r]*inv2);
        if (slab[rl] - lcb == cls){
          float cy = v;
          float s2 = fminf(fmaxf(1.f - cy*cy, 0.f), 1.f);
          float sy = sqrtf(s2);
          float ph = cy*COSM_ - sy*SINM_;
          if (!(cy - TH_ > 0.f)) ph = cy - MM_;
          phi_g[rowbase + rl] = ph;
          v = ph;
        }
        sm.mx[rl*33 + cls] = v;
      }
    }
  }
  __syncthreads();

  {
    int row  = tid >> 1;
    int half = tid & 1;
    int grow = rowbase + row;
    float se = 0.f;
    u64 pk = 0ull;
    #pragma unroll
    for (int c = 0; c < 16; ++c){
      int lc = half*16 + c;
      float v = sm.mx[row*33 + lc];
      se += __expf(S_*v - S_);
      u32 u = __float_as_uint(v);
      u = (v >= 0.f) ? (u | 0x80000000u) : ~u;
      u64 p = ((u64)u << 32) | (u32)~(u32)(ct*32 + lc);
      pk = (p > pk) ? p : pk;
    }
    se += __shfl_xor(se, 1);
    u32 lo = (u32)pk, hi2 = (u32)(pk >> 32);
    u32 plo = __shfl_xor(lo, 1), phi2 = __shfl_xor(hi2, 1);
    u64 po = ((u64)phi2 << 32) | plo;
    pk = (po > pk) ? po : pk;
    if (half == 0){
      atomicAdd(&sumexp_g[grow], se);
      atomicMax(&packed_g[grow], pk);
    }
  }
}

// ---------------- finalize: loss + prec1 ----------------
__global__ void k_final(const float* __restrict__ sumexp, const u64* __restrict__ packed,
                        const float* __restrict__ phi, const int* __restrict__ label,
                        float* __restrict__ out){
  int i = threadIdx.x;
  float lse  = S_ + logf(sumexp[i]);
  float loss = lse - S_ * phi[i];
  u32 pred = ~(u32)(packed[i] & 0xFFFFFFFFull);
  float corr = (pred == (u32)label[i]) ? 1.f : 0.f;
  float a = loss, b = corr;
  #pragma unroll
  for (int off = 1; off < 64; off <<= 1){ a += __shfl_xor(a, off); b += __shfl_xor(b, off); }
  __shared__ float sa[8], sb[8];
  if ((i & 63) == 0){ sa[i >> 6] = a; sb[i >> 6] = b; }
  __syncthreads();
  if (i == 0){
    float ta = 0.f, tb = 0.f;
    #pragma unroll
    for (int j = 0; j < 8; ++j){ ta += sa[j]; tb += sb[j]; }
    out[0] = ta / 512.f;
    out[1] = tb * (100.f / 512.f);
  }
}

extern "C" void kernel_launch(void* const* d_in, const int* in_sizes, int n_in,
                              void* d_out, int out_size, void* d_ws, size_t ws_size,
                              hipStream_t stream){
  const float* x     = (const float*)d_in[0];
  const int*   label = (const int*)d_in[1];
  const float* w     = (const float*)d_in[2];
  float* out = (float*)d_out;
  char* ws = (char*)d_ws;

  unsigned short* xn = (unsigned short*)ws;            // 524288 B
  float* sumexp = (float*)(ws + 524288);               // 2048 B
  u64*   packed = (u64*)(ws + 524288 + 2048);          // 4096 B
  float* phi    = (float*)(ws + 524288 + 2048 + 4096); // 2048 B
  unsigned short* wnb = (unsigned short*)(ws + 532480);// 307,200,000 B (Path A)

  const size_t needA = 532480ull + (size_t)CK_ * D_ * 2ull;

  k_init <<<1,    512, 0, stream>>>(sumexp, packed, phi);
  k_norm <<<B_/4, 256, 0, stream>>>(x, xn);
  if (ws_size >= needA){
    k_norm <<<CK_/4, 256, 0, stream>>>(w, wnb);
    k_gemm4<<<(CK_/BN)*4, 256, 0, stream>>>(xn, wnb, label, sumexp, packed, phi);
  } else {
    k_gemm_fused<<<(CK_/BN)*4, 256, 0, stream>>>(xn, w, label, sumexp, packed, phi);
  }
  k_final<<<1,    512, 0, stream>>>(sumexp, packed, phi, label, out);
}